// Round 3
// baseline (1433.056 us; speedup 1.0000x reference)
//
#include <hip/hip_runtime.h>
#include <hip/hip_cooperative_groups.h>

namespace cg = cooperative_groups;

// Problem constants (fixed by the reference)
#define N 2048
#define D 256
#define C 768          // 3*D
#define K2 512         // 2*D (concat [emb | msg])
#define V 2
#define L 16
#define NSTATE 15      // S_0..S_14 (step-15 mask provably empty)
#define NAPP 14        // encoder applications
#define MAXM 2048
#define UMAX 512       // union-row cap per variant (expected ~100)
#define TCAP 1024      // total masked entries cap per variant (expected ~100)

typedef __attribute__((ext_vector_type(8))) short bf16x8;
typedef __attribute__((ext_vector_type(4))) float f32x4;

__device__ __forceinline__ ushort bf16_rn(float x) {
  unsigned u = __float_as_uint(x);
  u += 0x7FFFu + ((u >> 16) & 1u);
  return (ushort)(u >> 16);
}
__device__ __forceinline__ float bf16_f(ushort h) {
  return __uint_as_float(((unsigned)h) << 16);
}

// Chunk-tiled A layout: element (row, k) lives at
//   ((row>>5)*8 + (k>>6))*2048 + (row&31)*64 + (k&63)
// so one (m-tile, k-chunk) = 2048 contiguous ushorts = 4 KB.
__device__ __forceinline__ size_t a_addr(int row, int k) {
  return ((size_t)(row >> 5) * 8 + (k >> 6)) * 2048 + (row & 31) * 64 + (k & 63);
}

// ---------------------------------------------------------------------------
// k_init: states0 = emb; A0 self bf16 split (chunked layout); Wt split;
// zero out / fillpos / mcnt / mark / ucnt.
// ---------------------------------------------------------------------------
__global__ __launch_bounds__(256) void k_init(
    const float* __restrict__ emb, const float* __restrict__ Ws,
    const float* __restrict__ Wn, float* __restrict__ states0,
    ushort* __restrict__ WtHi, ushort* __restrict__ WtLo,
    ushort* __restrict__ A0hi, ushort* __restrict__ A0lo,
    float* __restrict__ out, int* __restrict__ fillpos,
    int* __restrict__ mcnt, int* __restrict__ mark, int* __restrict__ ucnt) {
  size_t i = (size_t)blockIdx.x * 256 + threadIdx.x;
  size_t stride = (size_t)gridDim.x * 256;
  for (size_t x = i; x < (size_t)N * D; x += stride) {
    float v = emb[x];
    states0[x] = v;
    ushort h = bf16_rn(v);
    ushort l = bf16_rn(v - bf16_f(h));
    int r = (int)(x >> 8), cc = (int)(x & 255);
    size_t a = a_addr(r, cc);
    A0hi[a] = h;
    A0lo[a] = l;
  }
  for (size_t x = i; x < (size_t)D * K2; x += stride) {
    size_t cc = x >> 9, k = x & 511;  // Wt[n=cc][k]
    float v = (k < D) ? Ws[k * D + cc] : Wn[(k - D) * D + cc];
    ushort h = bf16_rn(v);
    WtHi[x] = h;
    WtLo[x] = bf16_rn(v - bf16_f(h));
  }
  for (size_t x = i; x < (size_t)N * C; x += stride) out[x] = 0.f;
  for (size_t x = i; x < N; x += stride) fillpos[x] = 0;
  for (size_t x = i; x < (size_t)V * N; x += stride) mark[x] = 0;
  for (size_t x = i; x < V * L; x += stride) mcnt[x] = 0;
  for (size_t x = i; x < V; x += stride) ucnt[x] = 0;
}

// ---------------------------------------------------------------------------
// CSR build (by dst, keeps multiplicity).  ei[0..E)=src, ei[E..2E)=dst.
// ---------------------------------------------------------------------------
__global__ void k_deg(const int* __restrict__ ei, int* __restrict__ fillpos, int E) {
  int e = blockIdx.x * 256 + threadIdx.x;
  if (e < E) atomicAdd(&fillpos[ei[E + e]], 1);
}

__global__ __launch_bounds__(256) void k_scan(int* __restrict__ fillpos,
                                              int* __restrict__ row_ptr) {
  __shared__ int part[256];
  __shared__ int base[257];
  int t = threadIdx.x;
  int v[8];
  int s = 0;
  for (int j = 0; j < 8; j++) { v[j] = fillpos[t * 8 + j]; s += v[j]; }
  part[t] = s;
  __syncthreads();
  if (t == 0) {
    int acc = 0;
    for (int q = 0; q < 256; q++) { base[q] = acc; acc += part[q]; }
    base[256] = acc;
  }
  __syncthreads();
  int acc = base[t];
  for (int j = 0; j < 8; j++) {
    row_ptr[t * 8 + j] = acc;
    fillpos[t * 8 + j] = acc;
    acc += v[j];
  }
  if (t == 255) row_ptr[N] = base[256];
}

__global__ void k_fill(const int* __restrict__ ei, int* __restrict__ fillpos,
                       int* __restrict__ csr_src, int E) {
  int e = blockIdx.x * 256 + threadIdx.x;
  if (e < E) {
    int dst = ei[E + e];
    int pos = atomicAdd(&fillpos[dst], 1);
    csr_src[pos] = ei[e];
  }
}

// ---------------------------------------------------------------------------
// k_meta: per (variant, step): has flag, distinct suffix list, compacted
// masked-place list + per-place destination bitmask (over tlist indices).
// ---------------------------------------------------------------------------
__global__ __launch_bounds__(256) void k_meta(
    const int* __restrict__ adj, const int* __restrict__ variants,
    int* __restrict__ hasA, int* __restrict__ tlistA,
    int* __restrict__ mcntA, int* __restrict__ mlistA, unsigned* __restrict__ mmaskA) {
  __shared__ int sh_has;
  __shared__ int sh_tl[L];
  __shared__ int sh_tc;
  int vi = blockIdx.x;
  int v = vi / L, i = vi % L;
  int t = threadIdx.x;
  int a = variants[vi];
  if (t == 0) {
    sh_has = 0;
    int cnt = 0;
    for (int j = i + 1; j < L; j++) {
      int x = variants[v * L + j];
      bool dup = false;
      for (int q = 0; q < cnt; q++) if (sh_tl[q] == x) dup = true;
      if (!dup) sh_tl[cnt++] = x;
    }
    sh_tc = cnt;
  }
  __syncthreads();
  int any = 0;
  for (int p = t; p < N; p += 256) any |= (adj[(size_t)a * N + p] != 0);
  if (any) atomicOr(&sh_has, 1);
  __syncthreads();
  int hasv = sh_has, tc = sh_tc;
  if (t == 0) {
    hasA[vi] = hasv;
    for (int q = 0; q < tc; q++) tlistA[vi * L + q] = sh_tl[q];
  }
  if (hasv) {
    for (int p = t; p < N; p += 256) {
      if (adj[(size_t)a * N + p] != 0) {
        unsigned bits = 0;
        for (int q = 0; q < tc; q++)
          if (adj[(size_t)p * N + sh_tl[q]] != 0) bits |= (1u << q);
        if (bits) {
          int slot = atomicAdd(&mcntA[vi], 1);
          mlistA[vi * MAXM + slot] = p;
          mmaskA[vi * MAXM + slot] = bits;
        }
      }
    }
  }
}

// ---------------------------------------------------------------------------
// Union-row slot assignment (two phases for ordering).
// ---------------------------------------------------------------------------
__global__ __launch_bounds__(64) void k_umark(
    const int* __restrict__ mcntA, const int* __restrict__ mlistA,
    int* __restrict__ mark, int* __restrict__ slotof, int* __restrict__ ucnt,
    int* __restrict__ ulist) {
  int vi = blockIdx.x, v = vi >> 4;
  int mc = mcntA[vi];
  for (int m = threadIdx.x; m < mc; m += 64) {
    int p = mlistA[vi * MAXM + m];
    if (atomicCAS(&mark[v * N + p], 0, 1) == 0) {
      int s = atomicAdd(&ucnt[v], 1);
      if (s < UMAX) {
        slotof[v * N + p] = s;
        ulist[v * UMAX + s] = p;
      }
    }
  }
}

__global__ __launch_bounds__(64) void k_uslot(
    const int* __restrict__ mcntA, const int* __restrict__ mlistA,
    const int* __restrict__ slotof, int* __restrict__ mslotA) {
  int vi = blockIdx.x, v = vi >> 4;
  int mc = mcntA[vi];
  for (int m = threadIdx.x; m < mc; m += 64) {
    int p = mlistA[vi * MAXM + m];
    mslotA[vi * MAXM + m] = slotof[v * N + p];
  }
}

// ---------------------------------------------------------------------------
// k_chain: the full 14-app encoder chain in ONE cooperative kernel.
// Grid 256 blocks x 256 threads; block b -> gemm tile (mb=b>>2: 32 rows,
// nb=b&3: 64 cols), msg rows [b*8, b*8+8).
// W tile (hi+lo, 130 KB) resident in LDS for all 14 apps; A streamed in
// contiguous 4 KB k-chunks with 2-deep register prefetch + LDS dbuf.
// LDS: W 66560 us + A 4*2304 us = 151552 B.
// ---------------------------------------------------------------------------
#define SM_WL 33280          // ushorts per W half (64 rows x 520)
#define SM_AB 66560          // A buffers base (ushorts)
#define SM_TOTAL_CHAIN 151552

__device__ __forceinline__ void msg_phase(
    const float* __restrict__ st, const int* __restrict__ row_ptr,
    const int* __restrict__ csr_src, ushort* __restrict__ Nh,
    ushort* __restrict__ Nl, int b, int wave, int lane) {
  for (int rr = 0; rr < 2; rr++) {
    int row = b * 8 + wave * 2 + rr;
    float4 acc = {0.f, 0.f, 0.f, 0.f};
    int e0 = row_ptr[row], e1 = row_ptr[row + 1];
    for (int e = e0; e < e1; e++) {
      const float4* r = (const float4*)(st + (size_t)csr_src[e] * D);
      float4 x = r[lane];
      acc.x += x.x; acc.y += x.y; acc.z += x.z; acc.w += x.w;
    }
    float vv[4] = {acc.x, acc.y, acc.z, acc.w};
    ushort h[4], l[4];
#pragma unroll
    for (int j = 0; j < 4; j++) {
      h[j] = bf16_rn(vv[j]);
      l[j] = bf16_rn(vv[j] - bf16_f(h[j]));
    }
    size_t ca = a_addr(row, D + lane * 4);
    *(ushort4*)&Nh[ca] = make_ushort4(h[0], h[1], h[2], h[3]);
    *(ushort4*)&Nl[ca] = make_ushort4(l[0], l[1], l[2], l[3]);
  }
}

__global__ __launch_bounds__(256) void k_chain(
    const ushort* __restrict__ WtHi, const ushort* __restrict__ WtLo,
    const float* __restrict__ bias, float* __restrict__ states,
    ushort* __restrict__ A0h, ushort* __restrict__ A0l,
    ushort* __restrict__ A1h, ushort* __restrict__ A1l,
    const int* __restrict__ row_ptr, const int* __restrict__ csr_src) {
  extern __shared__ __align__(16) ushort sm[];
  ushort* Wh = sm;                 // [64][520]
  ushort* Wl = sm + SM_WL;
  ushort* Ab = sm + SM_AB;         // [buf2][half2][32][72]
  cg::grid_group grid = cg::this_grid();
  const int tid = threadIdx.x, b = blockIdx.x;
  const int mb = b >> 2, nb = b & 3;
  const int wave = tid >> 6, lane = tid & 63, quad = lane >> 4, l16 = lane & 15;

  // W tile -> LDS (once)
  {
    const int n0 = nb * 64;
    for (int x = tid; x < 4096; x += 256) {
      int col = x >> 6, k8 = (x & 63) * 8;
      *(uint4*)&Wh[col * 520 + k8] = *(const uint4*)&WtHi[(size_t)(n0 + col) * K2 + k8];
      *(uint4*)&Wl[col * 520 + k8] = *(const uint4*)&WtLo[(size_t)(n0 + col) * K2 + k8];
    }
  }
  // initial msg gather for states[0] -> A0 msg cols
  msg_phase(states, row_ptr, csr_src, A0h, A0l, b, wave, lane);
  grid.sync();

  ushort* AH[2] = {A0h, A1h};
  ushort* AL[2] = {A0l, A1l};
  const int wrow = tid >> 3, wk = (tid & 7) * 8;

  for (int s = 0; s < NAPP; s++) {
    const ushort* Ah = AH[s & 1];
    const ushort* Al = AL[s & 1];
    ushort* Nh = AH[(s + 1) & 1];
    ushort* Nl = AL[(s + 1) & 1];
    float* nxt = states + (size_t)(s + 1) * N * D;

    f32x4 acc[2] = {};
    uint4 rh[2], rl[2];
    {
      size_t b0 = ((size_t)mb * 8 + 0) * 2048 + (size_t)tid * 8;
      size_t b1 = ((size_t)mb * 8 + 1) * 2048 + (size_t)tid * 8;
      rh[0] = *(const uint4*)&Ah[b0];
      rl[0] = *(const uint4*)&Al[b0];
      rh[1] = *(const uint4*)&Ah[b1];
      rl[1] = *(const uint4*)&Al[b1];
    }
#pragma unroll
    for (int c = 0; c < 8; c++) {
      int rb = c & 1;
      *(uint4*)&Ab[(size_t)((rb * 2 + 0) * 32 + wrow) * 72 + wk] = rh[rb];
      *(uint4*)&Ab[(size_t)((rb * 2 + 1) * 32 + wrow) * 72 + wk] = rl[rb];
      if (c + 2 < 8) {
        size_t bn = ((size_t)mb * 8 + c + 2) * 2048 + (size_t)tid * 8;
        rh[rb] = *(const uint4*)&Ah[bn];
        rl[rb] = *(const uint4*)&Al[bn];
      }
      __syncthreads();
#pragma unroll
      for (int kf = 0; kf < 2; kf++) {
        int ko = kf * 32 + quad * 8;
        bf16x8 whf = *(const bf16x8*)&Wh[(wave * 16 + l16) * 520 + c * 64 + ko];
        bf16x8 wlf = *(const bf16x8*)&Wl[(wave * 16 + l16) * 520 + c * 64 + ko];
#pragma unroll
        for (int mt = 0; mt < 2; mt++) {
          bf16x8 ahf = *(const bf16x8*)&Ab[(size_t)((rb * 2 + 0) * 32 + mt * 16 + l16) * 72 + ko];
          bf16x8 alf = *(const bf16x8*)&Ab[(size_t)((rb * 2 + 1) * 32 + mt * 16 + l16) * 72 + ko];
          acc[mt] = __builtin_amdgcn_mfma_f32_16x16x32_bf16(ahf, whf, acc[mt], 0, 0, 0);
          acc[mt] = __builtin_amdgcn_mfma_f32_16x16x32_bf16(ahf, wlf, acc[mt], 0, 0, 0);
          acc[mt] = __builtin_amdgcn_mfma_f32_16x16x32_bf16(alf, whf, acc[mt], 0, 0, 0);
        }
      }
      __syncthreads();  // reads of buf rb done before chunk c+2 overwrites it
    }
    // epilogue: states[s+1] fp32 + NA self split (chunked layout)
    {
      int col = nb * 64 + wave * 16 + l16;
      float bv = bias[col];
#pragma unroll
      for (int mt = 0; mt < 2; mt++) {
#pragma unroll
        for (int r = 0; r < 4; r++) {
          int row = mb * 32 + mt * 16 + quad * 4 + r;
          float v = fmaxf(acc[mt][r] + bv, 0.f);
          nxt[(size_t)row * D + col] = v;
          ushort h = bf16_rn(v);
          size_t ca = a_addr(row, col);
          Nh[ca] = h;
          Nl[ca] = bf16_rn(v - bf16_f(h));
        }
      }
    }
    grid.sync();
    if (s < NAPP - 1) {
      msg_phase(nxt, row_ptr, csr_src, Nh, Nl, b, wave, lane);
      grid.sync();
    }
  }
}

// ---------------------------------------------------------------------------
// k_pi: recurrence replay with LDS-resident union rows.  Grid V*12 blocks
// (64 cols each) x 64 threads.  Meta preloaded to LDS; final rows atomicAdd
// into zeroed d_out.  LDS: prow 512*64*4 + meta 3*TCAP*4 + tl 256*4.
// ---------------------------------------------------------------------------
#define SM_TOTAL_PI (UMAX * 64 * 4 + 3 * TCAP * 4 + 256 * 4)
__global__ __launch_bounds__(64) void k_pi(
    const float* __restrict__ states, float* __restrict__ out,
    const int* __restrict__ variants, const int* __restrict__ hasA,
    const int* __restrict__ tlistA, const int* __restrict__ mcntA,
    const int* __restrict__ mlistA, const unsigned* __restrict__ mmaskA,
    const int* __restrict__ mslotA, const int* __restrict__ ulist,
    const int* __restrict__ ucnt) {
  extern __shared__ __align__(16) float smf[];
  float* prow = smf;                                 // [UMAX][64]
  int* shp = (int*)(smf + UMAX * 64);                // [TCAP]
  int* shs = shp + TCAP;
  unsigned* shm = (unsigned*)(shs + TCAP);
  int* shtl = (int*)(shm + TCAP);                    // [256]
  int v = blockIdx.x / 12, cg = blockIdx.x % 12;
  int lane = threadIdx.x;
  int c = cg * 64 + lane;

  for (int i = lane; i < UMAX * 64; i += 64) prow[i] = 0.f;
  int offs[L + 1], mc_[L], has_[L];
  {
    int off = 0;
    for (int i = 0; i < L; i++) {
      offs[i] = off;
      mc_[i] = mcntA[v * L + i];
      has_[i] = hasA[v * L + i];
      off += mc_[i];
    }
    offs[L] = off;
  }
  for (int i = 0; i < L; i++) {
    int vi = v * L + i;
    for (int m = lane; m < mc_[i]; m += 64) {
      shp[offs[i] + m] = mlistA[vi * MAXM + m];
      shs[offs[i] + m] = mslotA[vi * MAXM + m] & (UMAX - 1);
      shm[offs[i] + m] = mmaskA[vi * MAXM + m];
    }
  }
  for (int x = lane; x < 256; x += 64) shtl[x] = tlistA[v * 256 + x];
  __syncthreads();

  float summary = 0.f;
  int k = 0;
  for (int i = 0; i < L; i++) {
    int vi = v * L + i;
    const float* embS = states + (size_t)(k < NSTATE ? k : NSTATE - 1) * N * D;
    int mc = mc_[i], o = offs[i];
    float embA = (cg >= 4 && cg < 8) ? embS[(size_t)variants[vi] * D + (c - 256)] : 0.f;
    float sacc = 0.f;
    for (int m = 0; m < mc; m++) {
      int slot = shs[o + m];
      float catv;
      if (cg < 4) {
        catv = embS[(size_t)shp[o + m] * D + c];
      } else if (cg < 8) {
        catv = embA;
      } else {
        catv = 0.f;
        unsigned bits = shm[o + m];
        while (bits) {
          int q = __ffs(bits) - 1;
          bits &= bits - 1;
          catv += embS[(size_t)shtl[i * 16 + q] * D + (c - 512)];
        }
      }
      float nv = prow[slot * 64 + lane] + catv;
      prow[slot * 64 + lane] = nv;
      sacc += nv;
    }
    summary += sacc;
    for (int m = 0; m < mc; m++) prow[shs[o + m] * 64 + lane] += summary;
    if (has_[i]) k++;
  }
  int U = ucnt[v];
  if (U > UMAX) U = UMAX;
  for (int u = 0; u < U; u++)
    atomicAdd(&out[(size_t)ulist[v * UMAX + u] * C + c], prow[u * 64 + lane]);
}

// ---------------------------------------------------------------------------
extern "C" void kernel_launch(void* const* d_in, const int* in_sizes, int n_in,
                              void* d_out, int out_size, void* d_ws, size_t ws_size,
                              hipStream_t stream) {
  const float* emb      = (const float*)d_in[0];
  const float* Ws       = (const float*)d_in[1];
  const float* Wn       = (const float*)d_in[2];
  const float* bias     = (const float*)d_in[3];
  const int*   variants = (const int*)d_in[4];
  const int*   adj      = (const int*)d_in[5];
  const int*   ei       = (const int*)d_in[6];
  const int    E        = in_sizes[6] / 2;
  float* out            = (float*)d_out;

  char* base = (char*)d_ws;
  float* states = (float*)base;            base += (size_t)NSTATE * N * D * 4;
  ushort* WtHi  = (ushort*)base;           base += (size_t)D * K2 * 2;
  ushort* WtLo  = (ushort*)base;           base += (size_t)D * K2 * 2;
  ushort* A0h   = (ushort*)base;           base += (size_t)N * K2 * 2;
  ushort* A0l   = (ushort*)base;           base += (size_t)N * K2 * 2;
  ushort* A1h   = (ushort*)base;           base += (size_t)N * K2 * 2;
  ushort* A1l   = (ushort*)base;           base += (size_t)N * K2 * 2;
  int* row_ptr  = (int*)base;              base += (N + 1) * 4;
  int* fillpos  = (int*)base;              base += N * 4;
  int* csr_src  = (int*)base;              base += (size_t)E * 4;
  int* hasA     = (int*)base;              base += V * L * 4;
  int* tlistA   = (int*)base;              base += V * L * L * 4;
  int* mcntA    = (int*)base;              base += V * L * 4;
  int* mlistA   = (int*)base;              base += (size_t)V * L * MAXM * 4;
  unsigned* mmaskA = (unsigned*)base;      base += (size_t)V * L * MAXM * 4;
  int* mslotA   = (int*)base;              base += (size_t)V * L * MAXM * 4;
  int* mark     = (int*)base;              base += (size_t)V * N * 4;
  int* slotof   = (int*)base;              base += (size_t)V * N * 4;
  int* ucnt     = (int*)base;              base += V * 4;
  int* ulist    = (int*)base;              base += V * UMAX * 4;

  hipFuncSetAttribute((const void*)k_chain,
                      hipFuncAttributeMaxDynamicSharedMemorySize, SM_TOTAL_CHAIN);
  hipFuncSetAttribute((const void*)k_pi,
                      hipFuncAttributeMaxDynamicSharedMemorySize, SM_TOTAL_PI);

  k_init<<<512, 256, 0, stream>>>(emb, Ws, Wn, states, WtHi, WtLo, A0h, A0l,
                                  out, fillpos, mcntA, mark, ucnt);
  k_deg<<<(E + 255) / 256, 256, 0, stream>>>(ei, fillpos, E);
  k_scan<<<1, 256, 0, stream>>>(fillpos, row_ptr);
  k_fill<<<(E + 255) / 256, 256, 0, stream>>>(ei, fillpos, csr_src, E);
  k_meta<<<V * L, 256, 0, stream>>>(adj, variants, hasA, tlistA, mcntA, mlistA, mmaskA);
  k_umark<<<V * L, 64, 0, stream>>>(mcntA, mlistA, mark, slotof, ucnt, ulist);
  k_uslot<<<V * L, 64, 0, stream>>>(mcntA, mlistA, slotof, mslotA);

  {
    void* args[] = {(void*)&WtHi, (void*)&WtLo, (void*)&bias, (void*)&states,
                    (void*)&A0h, (void*)&A0l, (void*)&A1h, (void*)&A1l,
                    (void*)&row_ptr, (void*)&csr_src};
    hipLaunchCooperativeKernel((const void*)k_chain, dim3(256), dim3(256),
                               args, SM_TOTAL_CHAIN, stream);
  }
  k_pi<<<V * 12, 64, SM_TOTAL_PI, stream>>>(states, out, variants, hasA, tlistA,
                                            mcntA, mlistA, mmaskA, mslotA,
                                            ulist, ucnt);
}

// Round 4
// 450.907 us; speedup vs baseline: 3.1782x; 3.1782x over previous
//
#include <hip/hip_runtime.h>

// Problem constants (fixed by the reference)
#define N 2048
#define D 256
#define C 768          // 3*D
#define V 2
#define L 16
#define NSTATE 15      // S_0..S_14 (step-15 mask provably empty)
#define NAPP 14        // encoder applications
#define MAXM 2048
#define UMAX 512       // union-row cap per variant (expected ~60)
#define TCAP 1024      // total masked entries cap per variant (expected ~60)

typedef __attribute__((ext_vector_type(8))) short bf16x8;
typedef __attribute__((ext_vector_type(4))) float f32x4;

__device__ __forceinline__ ushort bf16_rn(float x) {
  unsigned u = __float_as_uint(x);
  u += 0x7FFFu + ((u >> 16) & 1u);
  return (ushort)(u >> 16);
}
__device__ __forceinline__ float bf16_f(ushort h) {
  return __uint_as_float(((unsigned)h) << 16);
}

// Chunk-tiled operand layouts (chunk = 32 rows x 64 k = 2048 ushorts = 4 KB
// contiguous).  A: row in [0,2048), k in [0,256) -> 4 chunks per row-tile.
__device__ __forceinline__ size_t a_addr(int row, int k) {
  return ((size_t)(row >> 5) * 4 + (k >> 6)) * 2048 + (row & 31) * 64 + (k & 63);
}
// W^T: n in [0,512), k in [0,256).
__device__ __forceinline__ size_t wt_addr(int n, int k) {
  return ((size_t)(n >> 5) * 4 + (k >> 6)) * 2048 + (n & 31) * 64 + (k & 63);
}

// ---------------------------------------------------------------------------
// k_init: states0 = emb; A0 bf16 split (chunked); Wt=[W_self|W_nbr]^T split
// (chunked); zero out / fillpos / mcnt / mark / ucnt.
// ---------------------------------------------------------------------------
__global__ __launch_bounds__(256) void k_init(
    const float* __restrict__ emb, const float* __restrict__ Ws,
    const float* __restrict__ Wn, float* __restrict__ states0,
    ushort* __restrict__ WtHi, ushort* __restrict__ WtLo,
    ushort* __restrict__ A0hi, ushort* __restrict__ A0lo,
    float* __restrict__ out, int* __restrict__ fillpos,
    int* __restrict__ mcnt, int* __restrict__ mark, int* __restrict__ ucnt) {
  size_t i = (size_t)blockIdx.x * 256 + threadIdx.x;
  size_t stride = (size_t)gridDim.x * 256;
  for (size_t x = i; x < (size_t)N * D; x += stride) {
    float v = emb[x];
    states0[x] = v;
    ushort h = bf16_rn(v);
    ushort l = bf16_rn(v - bf16_f(h));
    size_t a = a_addr((int)(x >> 8), (int)(x & 255));
    A0hi[a] = h;
    A0lo[a] = l;
  }
  for (size_t x = i; x < (size_t)512 * 256; x += stride) {
    int n = (int)(x >> 8), k = (int)(x & 255);
    float v = (n < 256) ? Ws[(size_t)k * 256 + n] : Wn[(size_t)k * 256 + (n - 256)];
    ushort h = bf16_rn(v);
    size_t a = wt_addr(n, k);
    WtHi[a] = h;
    WtLo[a] = bf16_rn(v - bf16_f(h));
  }
  for (size_t x = i; x < (size_t)N * C; x += stride) out[x] = 0.f;
  for (size_t x = i; x < N; x += stride) fillpos[x] = 0;
  for (size_t x = i; x < (size_t)V * N; x += stride) mark[x] = 0;
  for (size_t x = i; x < V * L; x += stride) mcnt[x] = 0;
  for (size_t x = i; x < V; x += stride) ucnt[x] = 0;
}

// ---------------------------------------------------------------------------
// CSR build (by dst, keeps multiplicity).  ei[0..E)=src, ei[E..2E)=dst.
// ---------------------------------------------------------------------------
__global__ void k_deg(const int* __restrict__ ei, int* __restrict__ fillpos, int E) {
  int e = blockIdx.x * 256 + threadIdx.x;
  if (e < E) atomicAdd(&fillpos[ei[E + e]], 1);
}

__global__ __launch_bounds__(256) void k_scan(int* __restrict__ fillpos,
                                              int* __restrict__ row_ptr) {
  __shared__ int part[256];
  __shared__ int base[257];
  int t = threadIdx.x;
  int v[8];
  int s = 0;
  for (int j = 0; j < 8; j++) { v[j] = fillpos[t * 8 + j]; s += v[j]; }
  part[t] = s;
  __syncthreads();
  if (t == 0) {
    int acc = 0;
    for (int q = 0; q < 256; q++) { base[q] = acc; acc += part[q]; }
    base[256] = acc;
  }
  __syncthreads();
  int acc = base[t];
  for (int j = 0; j < 8; j++) {
    row_ptr[t * 8 + j] = acc;
    fillpos[t * 8 + j] = acc;
    acc += v[j];
  }
  if (t == 255) row_ptr[N] = base[256];
}

__global__ void k_fill(const int* __restrict__ ei, int* __restrict__ fillpos,
                       int* __restrict__ csr_src, int E) {
  int e = blockIdx.x * 256 + threadIdx.x;
  if (e < E) {
    int dst = ei[E + e];
    int pos = atomicAdd(&fillpos[dst], 1);
    csr_src[pos] = ei[e];
  }
}

// ---------------------------------------------------------------------------
// k_meta: per (variant, step): has flag, distinct suffix list, compacted
// masked-place list + per-place destination bitmask (over tlist indices).
// ---------------------------------------------------------------------------
__global__ __launch_bounds__(256) void k_meta(
    const int* __restrict__ adj, const int* __restrict__ variants,
    int* __restrict__ hasA, int* __restrict__ tlistA,
    int* __restrict__ mcntA, int* __restrict__ mlistA, unsigned* __restrict__ mmaskA) {
  __shared__ int sh_has;
  __shared__ int sh_tl[L];
  __shared__ int sh_tc;
  int vi = blockIdx.x;
  int v = vi / L, i = vi % L;
  int t = threadIdx.x;
  int a = variants[vi];
  if (t == 0) {
    sh_has = 0;
    int cnt = 0;
    for (int j = i + 1; j < L; j++) {
      int x = variants[v * L + j];
      bool dup = false;
      for (int q = 0; q < cnt; q++) if (sh_tl[q] == x) dup = true;
      if (!dup) sh_tl[cnt++] = x;
    }
    sh_tc = cnt;
  }
  __syncthreads();
  int any = 0;
  for (int p = t; p < N; p += 256) any |= (adj[(size_t)a * N + p] != 0);
  if (any) atomicOr(&sh_has, 1);
  __syncthreads();
  int hasv = sh_has, tc = sh_tc;
  if (t == 0) {
    hasA[vi] = hasv;
    for (int q = 0; q < tc; q++) tlistA[vi * L + q] = sh_tl[q];
  }
  if (hasv) {
    for (int p = t; p < N; p += 256) {
      if (adj[(size_t)a * N + p] != 0) {
        unsigned bits = 0;
        for (int q = 0; q < tc; q++)
          if (adj[(size_t)p * N + sh_tl[q]] != 0) bits |= (1u << q);
        if (bits) {
          int slot = atomicAdd(&mcntA[vi], 1);
          mlistA[vi * MAXM + slot] = p;
          mmaskA[vi * MAXM + slot] = bits;
        }
      }
    }
  }
}

// ---------------------------------------------------------------------------
// Union-row slot assignment (two phases for ordering).
// ---------------------------------------------------------------------------
__global__ __launch_bounds__(64) void k_umark(
    const int* __restrict__ mcntA, const int* __restrict__ mlistA,
    int* __restrict__ mark, int* __restrict__ slotof, int* __restrict__ ucnt,
    int* __restrict__ ulist) {
  int vi = blockIdx.x, v = vi >> 4;
  int mc = mcntA[vi];
  for (int m = threadIdx.x; m < mc; m += 64) {
    int p = mlistA[vi * MAXM + m];
    if (atomicCAS(&mark[v * N + p], 0, 1) == 0) {
      int s = atomicAdd(&ucnt[v], 1);
      if (s < UMAX) {
        slotof[v * N + p] = s;
        ulist[v * UMAX + s] = p;
      }
    }
  }
}

__global__ __launch_bounds__(64) void k_uslot(
    const int* __restrict__ mcntA, const int* __restrict__ mlistA,
    const int* __restrict__ slotof, int* __restrict__ mslotA) {
  int vi = blockIdx.x, v = vi >> 4;
  int mc = mcntA[vi];
  for (int m = threadIdx.x; m < mc; m += 64) {
    int p = mlistA[vi * MAXM + m];
    mslotA[vi * MAXM + m] = slotof[v * N + p];
  }
}

// ---------------------------------------------------------------------------
// k_gemm: Z = A @ [W_self|W_nbr]   (M=2048, K=256, N=512), bf16 3-product
// split, fp32 accum.  Grid (64,16) = 1024 blocks (4/CU, 16 waves/CU); block
// tile 32x32, 4 waves each one 16x16 mfma tile (2x2).  Chunk-tiled operands:
// each staged chunk is contiguous 4 KB (1 dwordx4/thread/buffer); register
// prefetch of chunk c+1 overlaps MFMA of chunk c.  LDS stride 72 ushorts
// (144 B) -> 2-way bank alias only (free, m136).
// C/D + A/B fragment mappings validated end-to-end in R2.
// ---------------------------------------------------------------------------
__global__ __launch_bounds__(256) void k_gemm(
    const ushort* __restrict__ Ah, const ushort* __restrict__ Al,
    const ushort* __restrict__ Wh_g, const ushort* __restrict__ Wl_g,
    float* __restrict__ Z) {
  __shared__ __align__(16) ushort Ash[32][72], Asl[32][72];
  __shared__ __align__(16) ushort Wsh[32][72], Wsl[32][72];
  const int tid = threadIdx.x, wave = tid >> 6, lane = tid & 63;
  const int quad = lane >> 4, l16 = lane & 15;
  const int wr = wave >> 1, wc = wave & 1;
  const int mb = blockIdx.x, nb = blockIdx.y;
  const int sr = tid >> 3, sc = (tid & 7) * 8;

  f32x4 acc = {0.f, 0.f, 0.f, 0.f};
  size_t abase = (size_t)mb * 4 * 2048 + (size_t)tid * 8;
  size_t wbase = (size_t)nb * 4 * 2048 + (size_t)tid * 8;
  uint4 ra  = *(const uint4*)&Ah[abase];
  uint4 rl  = *(const uint4*)&Al[abase];
  uint4 rwh = *(const uint4*)&Wh_g[wbase];
  uint4 rwl = *(const uint4*)&Wl_g[wbase];
#pragma unroll
  for (int c = 0; c < 4; c++) {
    *(uint4*)&Ash[sr][sc] = ra;
    *(uint4*)&Asl[sr][sc] = rl;
    *(uint4*)&Wsh[sr][sc] = rwh;
    *(uint4*)&Wsl[sr][sc] = rwl;
    __syncthreads();
    if (c < 3) {
      size_t o = (size_t)(c + 1) * 2048;
      ra  = *(const uint4*)&Ah[abase + o];
      rl  = *(const uint4*)&Al[abase + o];
      rwh = *(const uint4*)&Wh_g[wbase + o];
      rwl = *(const uint4*)&Wl_g[wbase + o];
    }
#pragma unroll
    for (int kf = 0; kf < 2; kf++) {
      int ko = kf * 32 + quad * 8;
      bf16x8 a_h = *(const bf16x8*)&Ash[wr * 16 + l16][ko];
      bf16x8 a_l = *(const bf16x8*)&Asl[wr * 16 + l16][ko];
      bf16x8 w_h = *(const bf16x8*)&Wsh[wc * 16 + l16][ko];
      bf16x8 w_l = *(const bf16x8*)&Wsl[wc * 16 + l16][ko];
      acc = __builtin_amdgcn_mfma_f32_16x16x32_bf16(a_h, w_h, acc, 0, 0, 0);
      acc = __builtin_amdgcn_mfma_f32_16x16x32_bf16(a_h, w_l, acc, 0, 0, 0);
      acc = __builtin_amdgcn_mfma_f32_16x16x32_bf16(a_l, w_h, acc, 0, 0, 0);
    }
    __syncthreads();
  }
  int col = nb * 32 + wc * 16 + l16;
  int row0 = mb * 32 + wr * 16 + quad * 4;
#pragma unroll
  for (int r = 0; r < 4; r++)
    Z[(size_t)(row0 + r) * 512 + col] = acc[r];
}

// ---------------------------------------------------------------------------
// k_comb: next[r] = relu(Z1[r] + sum_{e in in(r)} Z2[src_e] + b); writes
// states fp32 + bf16 split of next A (chunked layout).  Wave per row.
// ---------------------------------------------------------------------------
__global__ __launch_bounds__(256) void k_comb(
    const float* __restrict__ Z, const float* __restrict__ bias,
    const int* __restrict__ row_ptr, const int* __restrict__ csr_src,
    float* __restrict__ stnext, ushort* __restrict__ NAh,
    ushort* __restrict__ NAl) {
  int row = blockIdx.x * 4 + (threadIdx.x >> 6);
  int lane = threadIdx.x & 63;
  float4 acc = ((const float4*)(Z + (size_t)row * 512))[lane];   // Z1 self
  int e0 = row_ptr[row], e1 = row_ptr[row + 1];
  for (int e = e0; e < e1; e++) {
    const float4* z2 = (const float4*)(Z + (size_t)csr_src[e] * 512 + 256);
    float4 x = z2[lane];
    acc.x += x.x; acc.y += x.y; acc.z += x.z; acc.w += x.w;
  }
  float4 bv = ((const float4*)bias)[lane];
  float v0 = fmaxf(acc.x + bv.x, 0.f), v1 = fmaxf(acc.y + bv.y, 0.f);
  float v2 = fmaxf(acc.z + bv.z, 0.f), v3 = fmaxf(acc.w + bv.w, 0.f);
  *(float4*)(stnext + (size_t)row * D + lane * 4) = make_float4(v0, v1, v2, v3);
  ushort h0 = bf16_rn(v0), h1 = bf16_rn(v1), h2 = bf16_rn(v2), h3 = bf16_rn(v3);
  size_t ca = a_addr(row, lane * 4);
  *(ushort4*)&NAh[ca] = make_ushort4(h0, h1, h2, h3);
  *(ushort4*)&NAl[ca] = make_ushort4(
      bf16_rn(v0 - bf16_f(h0)), bf16_rn(v1 - bf16_f(h1)),
      bf16_rn(v2 - bf16_f(h2)), bf16_rn(v3 - bf16_f(h3)));
}

// ---------------------------------------------------------------------------
// k_pi: recurrence replay with LDS-resident union rows (validated R3).
// Grid V*12 blocks (64 cols each) x 64 threads; atomicAdd into zeroed d_out.
// ---------------------------------------------------------------------------
#define SM_TOTAL_PI (UMAX * 64 * 4 + 3 * TCAP * 4 + 256 * 4)
__global__ __launch_bounds__(64) void k_pi(
    const float* __restrict__ states, float* __restrict__ out,
    const int* __restrict__ variants, const int* __restrict__ hasA,
    const int* __restrict__ tlistA, const int* __restrict__ mcntA,
    const int* __restrict__ mlistA, const unsigned* __restrict__ mmaskA,
    const int* __restrict__ mslotA, const int* __restrict__ ulist,
    const int* __restrict__ ucnt) {
  extern __shared__ __align__(16) float smf[];
  float* prow = smf;                                 // [UMAX][64]
  int* shp = (int*)(smf + UMAX * 64);                // [TCAP]
  int* shs = shp + TCAP;
  unsigned* shm = (unsigned*)(shs + TCAP);
  int* shtl = (int*)(shm + TCAP);                    // [256]
  int v = blockIdx.x / 12, cg = blockIdx.x % 12;
  int lane = threadIdx.x;
  int c = cg * 64 + lane;

  for (int i = lane; i < UMAX * 64; i += 64) prow[i] = 0.f;
  int offs[L + 1], mc_[L], has_[L];
  {
    int off = 0;
    for (int i = 0; i < L; i++) {
      offs[i] = off;
      mc_[i] = mcntA[v * L + i];
      has_[i] = hasA[v * L + i];
      off += mc_[i];
    }
    offs[L] = off;
  }
  for (int i = 0; i < L; i++) {
    int vi = v * L + i;
    for (int m = lane; m < mc_[i]; m += 64) {
      shp[offs[i] + m] = mlistA[vi * MAXM + m];
      shs[offs[i] + m] = mslotA[vi * MAXM + m] & (UMAX - 1);
      shm[offs[i] + m] = mmaskA[vi * MAXM + m];
    }
  }
  for (int x = lane; x < 256; x += 64) shtl[x] = tlistA[v * 256 + x];
  __syncthreads();

  float summary = 0.f;
  int k = 0;
  for (int i = 0; i < L; i++) {
    int vi = v * L + i;
    const float* embS = states + (size_t)(k < NSTATE ? k : NSTATE - 1) * N * D;
    int mc = mc_[i], o = offs[i];
    float embA = (cg >= 4 && cg < 8) ? embS[(size_t)variants[vi] * D + (c - 256)] : 0.f;
    float sacc = 0.f;
    for (int m = 0; m < mc; m++) {
      int slot = shs[o + m];
      float catv;
      if (cg < 4) {
        catv = embS[(size_t)shp[o + m] * D + c];
      } else if (cg < 8) {
        catv = embA;
      } else {
        catv = 0.f;
        unsigned bits = shm[o + m];
        while (bits) {
          int q = __ffs(bits) - 1;
          bits &= bits - 1;
          catv += embS[(size_t)shtl[i * 16 + q] * D + (c - 512)];
        }
      }
      float nv = prow[slot * 64 + lane] + catv;
      prow[slot * 64 + lane] = nv;
      sacc += nv;
    }
    summary += sacc;
    for (int m = 0; m < mc; m++) prow[shs[o + m] * 64 + lane] += summary;
    if (has_[i]) k++;
  }
  int U = ucnt[v];
  if (U > UMAX) U = UMAX;
  for (int u = 0; u < U; u++)
    atomicAdd(&out[(size_t)ulist[v * UMAX + u] * C + c], prow[u * 64 + lane]);
}

// ---------------------------------------------------------------------------
extern "C" void kernel_launch(void* const* d_in, const int* in_sizes, int n_in,
                              void* d_out, int out_size, void* d_ws, size_t ws_size,
                              hipStream_t stream) {
  const float* emb      = (const float*)d_in[0];
  const float* Ws       = (const float*)d_in[1];
  const float* Wn       = (const float*)d_in[2];
  const float* bias     = (const float*)d_in[3];
  const int*   variants = (const int*)d_in[4];
  const int*   adj      = (const int*)d_in[5];
  const int*   ei       = (const int*)d_in[6];
  const int    E        = in_sizes[6] / 2;
  float* out            = (float*)d_out;

  char* base = (char*)d_ws;
  float* states = (float*)base;            base += (size_t)NSTATE * N * D * 4;
  float* Z      = (float*)base;            base += (size_t)N * 512 * 4;
  ushort* WtHi  = (ushort*)base;           base += (size_t)512 * 256 * 2;
  ushort* WtLo  = (ushort*)base;           base += (size_t)512 * 256 * 2;
  ushort* A0h   = (ushort*)base;           base += (size_t)N * D * 2;
  ushort* A0l   = (ushort*)base;           base += (size_t)N * D * 2;
  ushort* A1h   = (ushort*)base;           base += (size_t)N * D * 2;
  ushort* A1l   = (ushort*)base;           base += (size_t)N * D * 2;
  int* row_ptr  = (int*)base;              base += (N + 1) * 4;
  int* fillpos  = (int*)base;              base += N * 4;
  int* csr_src  = (int*)base;              base += (size_t)E * 4;
  int* hasA     = (int*)base;              base += V * L * 4;
  int* tlistA   = (int*)base;              base += V * L * L * 4;
  int* mcntA    = (int*)base;              base += V * L * 4;
  int* mlistA   = (int*)base;              base += (size_t)V * L * MAXM * 4;
  unsigned* mmaskA = (unsigned*)base;      base += (size_t)V * L * MAXM * 4;
  int* mslotA   = (int*)base;              base += (size_t)V * L * MAXM * 4;
  int* mark     = (int*)base;              base += (size_t)V * N * 4;
  int* slotof   = (int*)base;              base += (size_t)V * N * 4;
  int* ucnt     = (int*)base;              base += V * 4;
  int* ulist    = (int*)base;              base += V * UMAX * 4;

  hipFuncSetAttribute((const void*)k_pi,
                      hipFuncAttributeMaxDynamicSharedMemorySize, SM_TOTAL_PI);

  k_init<<<512, 256, 0, stream>>>(emb, Ws, Wn, states, WtHi, WtLo, A0h, A0l,
                                  out, fillpos, mcntA, mark, ucnt);
  k_deg<<<(E + 255) / 256, 256, 0, stream>>>(ei, fillpos, E);
  k_scan<<<1, 256, 0, stream>>>(fillpos, row_ptr);
  k_fill<<<(E + 255) / 256, 256, 0, stream>>>(ei, fillpos, csr_src, E);
  k_meta<<<V * L, 256, 0, stream>>>(adj, variants, hasA, tlistA, mcntA, mlistA, mmaskA);
  k_umark<<<V * L, 64, 0, stream>>>(mcntA, mlistA, mark, slotof, ucnt, ulist);
  k_uslot<<<V * L, 64, 0, stream>>>(mcntA, mlistA, slotof, mslotA);

  ushort* AH[2] = {A0h, A1h};
  ushort* AL[2] = {A0l, A1l};
  for (int s = 0; s < NAPP; s++) {
    int cur = s & 1, nxt = cur ^ 1;
    k_gemm<<<dim3(64, 16), 256, 0, stream>>>(AH[cur], AL[cur], WtHi, WtLo, Z);
    k_comb<<<N / 4, 256, 0, stream>>>(Z, bias, row_ptr, csr_src,
                                      states + (size_t)(s + 1) * N * D,
                                      AH[nxt], AL[nxt]);
  }
  k_pi<<<V * 12, 64, SM_TOTAL_PI, stream>>>(states, out, variants, hasA, tlistA,
                                            mcntA, mlistA, mmaskA, mslotA,
                                            ulist, ucnt);
}